// Round 14
// baseline (169.763 us; speedup 1.0000x reference)
//
#include <hip/hip_runtime.h>
#include <hip/hip_bf16.h>

typedef unsigned long long u64;
typedef unsigned int u32;
typedef __attribute__((ext_vector_type(4))) double f64x4;

#define NB   64
#define NPOS 1024
#define NOUT 25
#define NCLS 20
#define WROW 32            // f64 weights per channel row, padded to 256 B

// ---- workspace layout (bytes) ----
#define OFF_W64   0          // double wpad[512*32] = 131072
#define OFF_B64   131072     // double b64[25]      = 200 (pad to 131328)
#define OFF_ORDER 131328     // int    order[64*1024]   = 262144
#define OFF_SBOX  393472     // float4 sbox[64*1024]    = 1048576
#define OFF_SCLS  1442048    // int    scls[64*1024]    = 262144
#define OFF_VALID 1704192    // u64    validW[64*16]    = 8192
#define OFF_MASK  1712384    // u64    masksT[64][16][1024] = 8388608
#define OFF_SUMM  10100992   // u32    summ32[64][16]   = 4096
#define OFF_CNT   10105088   // int    cnt[64]          = 256 -> end 10105344

// ---------------- kernel 0: weights -> f64, layout [c][32] (pad 0) -----------
__global__ __launch_bounds__(256) void k_cvt(const float* __restrict__ w,
                                             const float* __restrict__ bias,
                                             double* __restrict__ wpad,
                                             double* __restrict__ b64)
{
    int idx = blockIdx.x * 256 + threadIdx.x;
    if (idx < 512 * WROW) {
        int c = idx >> 5, o = idx & 31;
        wpad[idx] = (o < NOUT) ? (double)w[o * 512 + c] : 0.0;
    }
    if (idx < NOUT) b64[idx] = (double)bias[idx];
}

// ---------------- f64 epilogue: sigmoid/softmax/argmax + box decode ----------
__device__ __forceinline__ void epilogue(const double* __restrict__ acc,
                                         const double* __restrict__ b64,
                                         int n, int gi,
                                         float* __restrict__ boxes_out,
                                         float* __restrict__ scores_out,
                                         float* __restrict__ cls_out)
{
    double p[NOUT];
#pragma unroll
    for (int o = 0; o < NOUT; ++o) p[o] = acc[o] + b64[o];

    double conf = 1.0 / (1.0 + exp(-p[0]));
    double m = p[1]; int ci = 0;
#pragma unroll
    for (int i = 2; i <= NCLS; ++i) {
        if (p[i] > m) { m = p[i]; ci = i - 1; }
    }
    double ssum = 0.0;
#pragma unroll
    for (int i = 0; i < NCLS; ++i) ssum += exp(p[1 + i] - m);
    double best = conf / ssum;

    int gx = n & 31, gy = n >> 5;
    double sx = 1.0 / (1.0 + exp(-p[21]));
    double sy = 1.0 / (1.0 + exp(-p[22]));
    double cx = (sx + (double)gx) * 32.0;
    double cy = (sy + (double)gy) * 32.0;
    double bw = exp(p[23]), bh = exp(p[24]);
    double x1 = (cx - bw * 0.5) * (1.0 / 1024.0);
    double y1 = (cy - bh * 0.5) * (1.0 / 1024.0);
    double x2 = (cx + bw * 0.5) * (1.0 / 1024.0);
    double y2 = (cy + bh * 0.5) * (1.0 / 1024.0);
    x1 = fmin(fmax(x1, 0.0), 1.0); y1 = fmin(fmax(y1, 0.0), 1.0);
    x2 = fmin(fmax(x2, 0.0), 1.0); y2 = fmin(fmax(y2, 0.0), 1.0);

    ((float4*)boxes_out)[gi] = make_float4((float)x1, (float)y1, (float)x2, (float)y2);
    scores_out[gi] = (float)best;
    cls_out[gi]    = (float)ci;
}

// ---------------- kernel 1: f64 MFMA GEMM, 32-pos tiles, 6 blocks/CU ---------
// Tile 32 pos x 32 out x K=512 in 32 chunks of 16 ch. 4 waves: pf=wv>>1
// (pos-frag), oh=wv&1 (out-half); 1 MFMA/wave/kstep. LDS 12.3 KB (pd
// unioned) + grid (32,64)=2048 blocks + lb(256,6) -> 6 blocks/CU = 6 w/SIMD
// (R12->R13 showed occupancy-proportional scaling). D row map self-calib.
__global__ __launch_bounds__(256, 6) void k_main(const float* __restrict__ feat,
                                                 const double* __restrict__ wpad_g,
                                                 const double* __restrict__ b64,
                                                 float* __restrict__ boxes_out,
                                                 float* __restrict__ scores_out,
                                                 float* __restrict__ cls_out)
{
    __shared__ __align__(16) char smem[12544];
    float*  AbF = (float*)smem;                    // [2][16*32] f32 = 4096 B
    double* BbF = (double*)(smem + 4096);          // [2][16*32] f64 = 8192 B
    double (*pd)[33] = (double(*)[33])smem;        // [32][33] f64, post-loop reuse

    const int b   = blockIdx.y;
    const int tid = threadIdx.x;
    const int l   = tid & 63;
    const int wv  = tid >> 6;
    const int pf  = wv >> 1;          // pos-frag (16 pos)
    const int oh  = wv & 1;           // out half (16 outs)
    const int n0  = blockIdx.x * 32;

    // --- runtime D-row calibration: A[m][0]=m, B[0][n]=1 => D[m][n]=m -------
    double ca = ((l >> 4) == 0) ? (double)(l & 15) : 0.0;
    double cb = ((l >> 4) == 0) ? 1.0 : 0.0;
    f64x4 cd = {0.0, 0.0, 0.0, 0.0};
    cd = __builtin_amdgcn_mfma_f64_16x16x4f64(ca, cb, cd, 0, 0, 0);
    int rmap[4];
#pragma unroll
    for (int v = 0; v < 4; ++v) {
        int r = (int)(cd[v] + 0.5);
        rmap[v] = (r < 0) ? 0 : (r > 15 ? 15 : r);
    }

    const float* __restrict__ featb = feat + (size_t)b * 512 * NPOS + n0;
    // A staging: tid<128: ch = tid>>3, posquad = tid&7 (float4)
    const int ach = tid >> 3, apq = tid & 7;
    // B staging: ch = tid>>4, outpair = tid&15 (double2)
    const int bch = tid >> 4, bop = tid & 15;

#define A_SRC(C0) (((const float4*)(featb + (size_t)((C0) + ach) * NPOS)) + apq)
#define B_SRC(C0) (((const double2*)(wpad_g + (size_t)((C0) + bch) * WROW)) + bop)
#define A_DST(BUF) ((float4*)(AbF + (BUF)*512 + ach*32 + apq*4))
#define B_DST(BUF) ((double2*)(BbF + (BUF)*512 + bch*32 + bop*2))

    f64x4 acc = {0.0, 0.0, 0.0, 0.0};

    // prologue: stage chunk 0
    float4  ra; double2 rb;
    if (tid < 128) { ra = *A_SRC(0); }
    rb = *B_SRC(0);
    if (tid < 128) { *A_DST(0) = ra; }
    *B_DST(0) = rb;
    __syncthreads();

#pragma unroll 1
    for (int t = 0; t < 32; ++t) {
        const int buf = t & 1;
        const bool more = (t + 1) < 32;
        const int c1 = (t + 1) * 16;
        if (more) {                       // issue next-chunk loads early
            if (tid < 128) ra = *A_SRC(c1);
            rb = *B_SRC(c1);
        }
#pragma unroll
        for (int s = 0; s < 4; ++s) {     // 4 k-steps x 4 ch
            const int rowA = buf*512 + (4*s + (l >> 4)) * 32 + pf * 16 + (l & 15);
            const int rowB = buf*512 + (4*s + (l >> 4)) * 32 + oh * 16 + (l & 15);
            double av = (double)AbF[rowA];
            double bv = BbF[rowB];
            acc = __builtin_amdgcn_mfma_f64_16x16x4f64(av, bv, acc, 0, 0, 0);
        }
        if (more) {                       // write next chunk into alt buffer
            if (tid < 128) *A_DST(buf ^ 1) = ra;
            *B_DST(buf ^ 1) = rb;
        }
        __syncthreads();
    }
#undef A_SRC
#undef B_SRC
#undef A_DST
#undef B_DST

    // dump D to LDS as [pos][out] with calibrated row map (smem reused)
#pragma unroll
    for (int v = 0; v < 4; ++v)
        pd[pf * 16 + rmap[v]][oh * 16 + (l & 15)] = acc[v];
    __syncthreads();

    if (tid < 32) {
        double accv[NOUT];
#pragma unroll
        for (int o = 0; o < NOUT; ++o) accv[o] = pd[tid][o];
        int n = n0 + tid;
        epilogue(accv, b64, n, b * NPOS + n, boxes_out, scores_out, cls_out);
    }
}

// ---------------- kernel 2: per-batch bitonic sort (desc score, stable) ------
__global__ __launch_bounds__(512) void k_sort(const float* __restrict__ scores,
                                              const float* __restrict__ boxes,
                                              const float* __restrict__ cls,
                                              int* __restrict__ order,
                                              float4* __restrict__ sbox,
                                              int* __restrict__ scls,
                                              u64* __restrict__ validW,
                                              u32* __restrict__ summ32,
                                              int* __restrict__ cnt)
{
    __shared__ u64 key[NPOS];
    __shared__ u64 vw[16];
    int b = blockIdx.x, tid = threadIdx.x;

    for (int ppos = tid; ppos < NPOS; ppos += 512) {
        u32 bits = __float_as_uint(scores[b * NPOS + ppos]);
        u32 d = ~(bits | 0x80000000u);   // descending-monotone key (scores >= 0)
        key[ppos] = ((u64)d << 32) | (u32)ppos;
    }
    if (tid < 16) { vw[tid] = 0ull; summ32[b * 16 + tid] = 0u; }
    if (tid == 0) cnt[b] = 0;
    __syncthreads();

    for (int k = 2; k <= NPOS; k <<= 1) {
        for (int j = k >> 1; j > 0; j >>= 1) {
            for (int idx = tid; idx < NPOS; idx += 512) {
                int l = idx ^ j;
                if (l > idx) {
                    u64 a = key[idx], c = key[l];
                    bool up = ((idx & k) == 0);
                    if ((a > c) == up) { key[idx] = c; key[l] = a; }
                }
            }
            __syncthreads();
        }
    }

    for (int ppos = tid; ppos < NPOS; ppos += 512) {
        u64 kk = key[ppos];
        int idx = (int)(kk & 0xffffffffu);
        order[b * NPOS + ppos] = idx;
        sbox [b * NPOS + ppos] = ((const float4*)boxes)[b * NPOS + idx];
        scls [b * NPOS + ppos] = (int)cls[b * NPOS + idx];
        u32 sb = (~(u32)(kk >> 32)) & 0x7fffffffu;
        float sc = __uint_as_float(sb);
        if (sc > 0.01f) atomicOr(&vw[ppos >> 6], 1ull << (ppos & 63));
    }
    __syncthreads();
    if (tid < 16) validW[b * 16 + tid] = vw[tid];
}

// ---------------- kernel 3: suppression mask + last-block inline scan --------
// Sparse mask store (summ32-flagged). The 64th finishing block of each batch
// (device-scope release/acquire via threadfence+atomicAdd) runs the scan
// inline, eliminating the k_scan launch.
__global__ __launch_bounds__(64) void k_mask(const float4* __restrict__ sbox,
                                             const int* __restrict__ scls,
                                             u64* __restrict__ masksT,
                                             u32* __restrict__ summ32,
                                             const u64* __restrict__ validW,
                                             const int* __restrict__ order,
                                             int* __restrict__ cnt,
                                             float* __restrict__ keep_out)
{
    __shared__ float4 boxl[256];
    __shared__ float2 acl[256];
    const int wc  = blockIdx.x;
    const int w   = wc >> 2, chunk = wc & 3;
    const int b   = blockIdx.y;
    const int lane = threadIdx.x;
    const int i0   = chunk * 256;
    const int imax = (w + 1) * 64;
    u64* __restrict__ mcol = masksT + (((size_t)b * 16 + w) << 10);

    int iend = imax - i0;
    if (iend > 256) iend = 256;

    if (iend > 0) {
        const int jg = w * 64 + lane;
        float4 bj = sbox[b * NPOS + jg];
        float  aj = (bj.z - bj.x) * (bj.w - bj.y);
        int    cj = scls[b * NPOS + jg];

        for (int i = lane; i < iend; i += 64) {
            float4 bb = sbox[b * NPOS + i0 + i];
            boxl[i] = bb;
            acl[i]  = make_float2((bb.z - bb.x) * (bb.w - bb.y),
                                  __int_as_float(scls[b * NPOS + i0 + i]));
        }
        __syncthreads();

#pragma unroll 1
        for (int t = 0; t < 256; t += 64) {
            if (t >= iend) break;
            u64 myword = 0ull;
#pragma unroll 1
            for (int s = 0; s < 64; s += 8) {
                u64 bits[8];
#pragma unroll
                for (int u = 0; u < 8; ++u) {
                    int i = t + s + u;
                    float4 bi = boxl[i];
                    float2 ac = acl[i];
                    float xx1 = fmaxf(bi.x, bj.x), yy1 = fmaxf(bi.y, bj.y);
                    float xx2 = fminf(bi.z, bj.z), yy2 = fminf(bi.w, bj.w);
                    float ww = fmaxf(1e-28f, xx2 - xx1);
                    float hh = fmaxf(1e-28f, yy2 - yy1);
                    float inter = ww * hh;
                    float uni = ac.x + aj - inter;
                    bool sup = (__float_as_int(ac.y) == cj) && (uni > 0.0f) &&
                               (inter > 0.5f * uni) && (jg > i0 + i) && (i < iend);
                    bits[u] = __ballot(sup);
                }
#pragma unroll
                for (int u = 0; u < 8; ++u)
                    myword = (lane == s + u) ? bits[u] : myword;
            }
            bool nz = __any(myword != 0ull);
            if (nz) {
                mcol[i0 + t + lane] = myword;
                if (lane == 0)
                    atomicOr(&summ32[b * 16 + ((i0 + t) >> 6)], 1u << w);
            }
        }
    }

    // ---- last-block-done: the 64th block of batch b scans inline ----
    __threadfence();
    int done = 0;
    if (lane == 0) done = atomicAdd(&cnt[b], 1);
    done = __shfl(done, 0);
    if (done != 63) return;
    __threadfence();

    u64 keep = (lane < 16) ? validW[b * 16 + lane] : 0ull;
    u32 sv   = (lane < 16) ? summ32[b * 16 + lane] : 0u;
    const u64* M = masksT + ((size_t)b << 14);
    int myrow = lane >> 4;
    int myw   = lane & 15;

#pragma unroll 1
    for (int G = 0; G < 16; ++G) {
        u32 gm = (u32)__shfl((int)sv, G);
        if (gm == 0u) continue;
#pragma unroll 1
        for (int g4 = 0; g4 < 16; ++g4) {
            u64 cur = 0ull;
            if ((gm >> myw) & 1u)
                cur = M[((size_t)myw << 10) + G * 64 + g4 * 4 + myrow];
            if (__any(cur != 0ull)) {
#pragma unroll
                for (int r = 0; r < 4; ++r) {
                    int i = G * 64 + g4 * 4 + r;
                    u64 kw = __shfl(keep, i >> 6);
                    if ((kw >> (i & 63)) & 1ull) {
                        u64 mm = __shfl(cur, r * 16 + myw);
                        if (lane < 16) keep &= ~mm;
                    }
                }
            }
        }
    }

#pragma unroll
    for (int t = 0; t < 16; ++t) {
        int ppos = t * 64 + lane;
        u64 kw = __shfl(keep, t);
        float v = ((kw >> lane) & 1ull) ? 1.0f : 0.0f;
        keep_out[b * NPOS + order[b * NPOS + ppos]] = v;
    }
}

// ------------------------------------------------------------------------------
extern "C" void kernel_launch(void* const* d_in, const int* in_sizes, int n_in,
                              void* d_out, int out_size, void* d_ws, size_t ws_size,
                              hipStream_t stream)
{
    const float* feat = (const float*)d_in[0];
    const float* w    = (const float*)d_in[1];
    const float* bias = (const float*)d_in[2];

    float* out = (float*)d_out;
    float* boxes_out  = out;
    float* scores_out = out + NB * NPOS * 4;
    float* cls_out    = out + NB * NPOS * 5;
    float* keep_out   = out + NB * NPOS * 6;

    char* ws = (char*)d_ws;
    double* wpad  = (double*)(ws + OFF_W64);
    double* b64   = (double*)(ws + OFF_B64);
    int*    order = (int*)   (ws + OFF_ORDER);
    float4* sbox  = (float4*)(ws + OFF_SBOX);
    int*    scls  = (int*)   (ws + OFF_SCLS);
    u64*    validW= (u64*)   (ws + OFF_VALID);
    u64*    masksT= (u64*)   (ws + OFF_MASK);
    u32*    summ32= (u32*)   (ws + OFF_SUMM);
    int*    cnt   = (int*)   (ws + OFF_CNT);

    hipLaunchKernelGGL(k_cvt,  dim3(64),     dim3(256), 0, stream, w, bias, wpad, b64);
    hipLaunchKernelGGL(k_main, dim3(32, 64), dim3(256), 0, stream, feat, wpad, b64,
                       boxes_out, scores_out, cls_out);
    hipLaunchKernelGGL(k_sort, dim3(64),     dim3(512), 0, stream, scores_out,
                       boxes_out, cls_out, order, sbox, scls, validW, summ32, cnt);
    hipLaunchKernelGGL(k_mask, dim3(64, 64), dim3(64),  0, stream, sbox, scls,
                       masksT, summ32, validW, order, cnt, keep_out);
}